// Round 1
// baseline (11379.890 us; speedup 1.0000x reference)
//
#include <hip/hip_runtime.h>
#include <math.h>

#define BB 256
#define TT 64
#define EMBD 256
#define UU 512
#define GG 2048   // 4*U

__device__ __forceinline__ float sigmoidf_(float x) { return 1.0f / (1.0f + expf(-x)); }

// ---------------- mean-pool over 10x10 spatial ----------------
// grid (2048/256, B), block 256
__global__ void pool_kernel(const float* __restrict__ enc, float* __restrict__ pooled) {
    int b = blockIdx.y;
    int e = blockIdx.x * 256 + threadIdx.x;
    const float* p = enc + (size_t)b * 100 * 2048 + e;
    float s = 0.f;
    #pragma unroll 4
    for (int i = 0; i < 100; ++i) s += p[(size_t)i * 2048];
    pooled[(size_t)b * 2048 + e] = s * 0.01f;
}

// ---------------- embedding gather ----------------
// grid (B*T), block 256 (EMB=256)
__global__ void embed_kernel(const int* __restrict__ seq, const float* __restrict__ emb,
                             float* __restrict__ tok) {
    int i = blockIdx.x;           // b*T + t
    int e = threadIdx.x;
    int id = seq[i];
    tok[(size_t)i * EMBD + e] = emb[(size_t)id * EMBD + e];
}

// ---------------- fused LSTM step: z = [x_t, h] @ [Wi; Wh] + b, gates, mask ----------------
// grid (U/32=16, B/32=8, 2 dirs), block 256.
// Tile: 32 batch rows x 32 h-cols (x4 gate blocks). 2x2 micro-tile per thread per gate.
// h/c double-buffered across steps (hin/hout are distinct buffers).
__global__ void lstm_step_kernel(const float* __restrict__ x, int D,
                                 const int* __restrict__ seq,
                                 const float* __restrict__ WiF, const float* __restrict__ WhF, const float* __restrict__ bF,
                                 const float* __restrict__ WiB, const float* __restrict__ WhB, const float* __restrict__ bB,
                                 const float* __restrict__ hin_all, float* __restrict__ hout_all,
                                 const float* __restrict__ cin_all, float* __restrict__ cout_all,
                                 float* __restrict__ seqout, int s) {
    const int dir = blockIdx.z;
    const int t = dir ? (TT - 1 - s) : s;
    const float* Wi   = dir ? WiB : WiF;   // [D, 2048]
    const float* Wh   = dir ? WhB : WhF;   // [U, 2048]
    const float* bias = dir ? bB  : bF;    // [2048]
    const float* hin  = hin_all  + (size_t)dir * BB * UU;
    float*       hout = hout_all + (size_t)dir * BB * UU;
    const float* cin  = cin_all  + (size_t)dir * BB * UU;
    float*       cout = cout_all + (size_t)dir * BB * UU;

    const int row0 = blockIdx.y * 32;
    const int col0 = blockIdx.x * 32;
    const int tid = threadIdx.x;
    const int tx = tid & 15, ty = tid >> 4;

    __shared__ float As[16][33];    // [k][row], +1 pad
    __shared__ float Bs[16][128];   // [k][gate*32 + col]

    float acc[4][2][2];
    #pragma unroll
    for (int g = 0; g < 4; ++g)
        #pragma unroll
        for (int r = 0; r < 2; ++r)
            #pragma unroll
            for (int c = 0; c < 2; ++c) acc[g][r][c] = 0.f;

    const int Ktot = D + UU;
    for (int k0 = 0; k0 < Ktot; k0 += 16) {
        // A tile: 32 rows x 16 k (coalesced over k, 16 floats/run)
        {
            int kk = tid & 15, r = tid >> 4;   // r 0..15
            int k = k0 + kk;
            #pragma unroll
            for (int j = 0; j < 2; ++j) {
                int rr = r + j * 16;
                int b = row0 + rr;
                float v;
                if (k < D) v = x[((size_t)b * TT + t) * D + k];
                else       v = hin[(size_t)b * UU + (k - D)];
                As[kk][rr] = v;
            }
        }
        // B tile: 16 k x (4 gates x 32 cols)
        {
            #pragma unroll
            for (int j = 0; j < 8; ++j) {
                int flat = tid + j * 256;
                int kk = flat >> 7;
                int gc = flat & 127;
                int g = gc >> 5, c = gc & 31;
                int k = k0 + kk;
                int colg = g * UU + col0 + c;
                float v;
                if (k < D) v = Wi[(size_t)k * GG + colg];
                else       v = Wh[(size_t)(k - D) * GG + colg];
                Bs[kk][gc] = v;
            }
        }
        __syncthreads();
        #pragma unroll
        for (int kk = 0; kk < 16; ++kk) {
            float a0 = As[kk][ty * 2 + 0];
            float a1 = As[kk][ty * 2 + 1];
            #pragma unroll
            for (int g = 0; g < 4; ++g) {
                float w0 = Bs[kk][g * 32 + tx * 2 + 0];
                float w1 = Bs[kk][g * 32 + tx * 2 + 1];
                acc[g][0][0] += a0 * w0;
                acc[g][0][1] += a0 * w1;
                acc[g][1][0] += a1 * w0;
                acc[g][1][1] += a1 * w1;
            }
        }
        __syncthreads();
    }

    // epilogue: gates (Keras order i,f,g,o), masked state carry
    #pragma unroll
    for (int r = 0; r < 2; ++r) {
        int b = row0 + ty * 2 + r;
        bool m = (seq[b * TT + t] != 0);
        #pragma unroll
        for (int c = 0; c < 2; ++c) {
            int col = col0 + tx * 2 + c;
            float zi = acc[0][r][c] + bias[0 * UU + col];
            float zf = acc[1][r][c] + bias[1 * UU + col];
            float zg = acc[2][r][c] + bias[2 * UU + col];
            float zo = acc[3][r][c] + bias[3 * UU + col];
            float ig = sigmoidf_(zi), fg = sigmoidf_(zf);
            float gg = tanhf(zg),     og = sigmoidf_(zo);
            float cprev = cin[(size_t)b * UU + col];
            float cnew  = fg * cprev + ig * gg;
            float hnew  = og * tanhf(cnew);
            float hprev = hin[(size_t)b * UU + col];
            float hv = m ? hnew : hprev;
            float cv = m ? cnew : cprev;
            hout[(size_t)b * UU + col] = hv;
            cout[(size_t)b * UU + col] = cv;
            if (seqout) seqout[((size_t)b * TT + t) * (2 * UU) + dir * UU + col] = hv;
        }
    }
}

// ---------------- dense: C = act(A@W + b), M x N, K multiple of 16 ----------------
// grid (N/32, M/32), block 256
__global__ void dense_kernel(const float* __restrict__ A, const float* __restrict__ W,
                             const float* __restrict__ bias, float* __restrict__ C,
                             int M, int N, int K, int act) {
    const int row0 = blockIdx.y * 32;
    const int col0 = blockIdx.x * 32;
    const int tid = threadIdx.x;
    const int tx = tid & 15, ty = tid >> 4;
    __shared__ float As[16][33];
    __shared__ float Bs[16][32];
    float acc[2][2] = {{0.f, 0.f}, {0.f, 0.f}};
    for (int k0 = 0; k0 < K; k0 += 16) {
        {
            int kk = tid & 15, r = tid >> 4;
            #pragma unroll
            for (int j = 0; j < 2; ++j) {
                int rr = r + j * 16;
                As[kk][rr] = A[(size_t)(row0 + rr) * K + k0 + kk];
            }
        }
        {
            #pragma unroll
            for (int j = 0; j < 2; ++j) {
                int flat = tid + j * 256;
                int kk = flat >> 5, c = flat & 31;
                Bs[kk][c] = W[(size_t)(k0 + kk) * N + col0 + c];
            }
        }
        __syncthreads();
        #pragma unroll
        for (int kk = 0; kk < 16; ++kk) {
            float a0 = As[kk][ty * 2], a1 = As[kk][ty * 2 + 1];
            float w0 = Bs[kk][tx * 2], w1 = Bs[kk][tx * 2 + 1];
            acc[0][0] += a0 * w0; acc[0][1] += a0 * w1;
            acc[1][0] += a1 * w0; acc[1][1] += a1 * w1;
        }
        __syncthreads();
    }
    #pragma unroll
    for (int r = 0; r < 2; ++r)
        #pragma unroll
        for (int c = 0; c < 2; ++c) {
            int row = row0 + ty * 2 + r, col = col0 + tx * 2 + c;
            float v = acc[r][c] + bias[col];
            if (act == 1) v = fmaxf(v, 0.f);
            C[(size_t)row * N + col] = v;
        }
}

// ---------------- feats = [pooled | h2f | h2b] ----------------
__global__ void concat_kernel(const float* __restrict__ pooled, const float* __restrict__ h2,
                              float* __restrict__ feats) {
    int b = blockIdx.x;
    for (int j = threadIdx.x; j < 3072; j += 256) {
        float v;
        if (j < 2048) v = pooled[(size_t)b * 2048 + j];
        else {
            int u = j - 2048;
            int dir = u >> 9;
            int uu = u & 511;
            v = h2[((size_t)dir * BB + b) * UU + uu];
        }
        feats[(size_t)b * 3072 + j] = v;
    }
}

// ---------------- out = sigmoid(x2 @ W3 + b3), K=512 ----------------
// grid (B), block 256
__global__ void final_kernel(const float* __restrict__ x2, const float* __restrict__ W3,
                             const float* __restrict__ b3, float* __restrict__ out) {
    int b = blockIdx.x;
    int tid = threadIdx.x;
    float v = x2[(size_t)b * 512 + tid] * W3[tid]
            + x2[(size_t)b * 512 + 256 + tid] * W3[256 + tid];
    for (int off = 32; off > 0; off >>= 1) v += __shfl_down(v, off, 64);
    __shared__ float wsum[4];
    if ((tid & 63) == 0) wsum[tid >> 6] = v;
    __syncthreads();
    if (tid == 0) {
        float s = wsum[0] + wsum[1] + wsum[2] + wsum[3] + b3[0];
        out[b] = 1.0f / (1.0f + expf(-s));
    }
}

extern "C" void kernel_launch(void* const* d_in, const int* in_sizes, int n_in,
                              void* d_out, int out_size, void* d_ws, size_t ws_size,
                              hipStream_t stream) {
    const float* enc    = (const float*)d_in[0];
    const int*   seq    = (const int*)  d_in[1];
    const float* emb    = (const float*)d_in[2];
    const float* l1f_Wi = (const float*)d_in[3];
    const float* l1f_Wh = (const float*)d_in[4];
    const float* l1f_b  = (const float*)d_in[5];
    const float* l1b_Wi = (const float*)d_in[6];
    const float* l1b_Wh = (const float*)d_in[7];
    const float* l1b_b  = (const float*)d_in[8];
    const float* l2f_Wi = (const float*)d_in[9];
    const float* l2f_Wh = (const float*)d_in[10];
    const float* l2f_b  = (const float*)d_in[11];
    const float* l2b_Wi = (const float*)d_in[12];
    const float* l2b_Wh = (const float*)d_in[13];
    const float* l2b_b  = (const float*)d_in[14];
    const float* W1     = (const float*)d_in[15];
    const float* b1     = (const float*)d_in[16];
    const float* W2     = (const float*)d_in[17];
    const float* b2     = (const float*)d_in[18];
    const float* W3     = (const float*)d_in[19];
    const float* b3     = (const float*)d_in[20];

    // workspace layout (floats); total ~94.9 MB
    float* ws = (float*)d_ws;
    float* tok      = ws;                       // 256*64*256     = 4,194,304
    float* lstm1out = tok + 4194304;            // 256*64*1024    = 16,777,216
    float* pooled   = lstm1out + 16777216;      // 256*2048       = 524,288
    float* feats    = pooled + 524288;          // 256*3072       = 786,432
    float* x1       = feats + 786432;           // 256*1024       = 262,144
    float* x2       = x1 + 262144;              // 256*512        = 131,072
    float* hA       = x2 + 131072;              // 2*256*512      = 262,144
    float* hB       = hA + 262144;
    float* cA       = hB + 262144;
    float* cB       = cA + 262144;

    pool_kernel<<<dim3(8, BB), 256, 0, stream>>>(enc, pooled);
    embed_kernel<<<dim3(BB * TT), 256, 0, stream>>>(seq, emb, tok);

    // -------- BiLSTM layer 1 (D=256, writes lstm1out) --------
    hipMemsetAsync(hA, 0, 262144 * sizeof(float), stream);
    hipMemsetAsync(cA, 0, 262144 * sizeof(float), stream);
    for (int s = 0; s < TT; ++s) {
        const float* hin = (s & 1) ? hB : hA;
        float*      hout = (s & 1) ? hA : hB;
        const float* cin = (s & 1) ? cB : cA;
        float*      cout = (s & 1) ? cA : cB;
        lstm_step_kernel<<<dim3(16, 8, 2), 256, 0, stream>>>(tok, EMBD, seq,
            l1f_Wi, l1f_Wh, l1f_b, l1b_Wi, l1b_Wh, l1b_b,
            hin, hout, cin, cout, lstm1out, s);
    }

    // -------- BiLSTM layer 2 (D=1024, final state only) --------
    hipMemsetAsync(hA, 0, 262144 * sizeof(float), stream);
    hipMemsetAsync(cA, 0, 262144 * sizeof(float), stream);
    for (int s = 0; s < TT; ++s) {
        const float* hin = (s & 1) ? hB : hA;
        float*      hout = (s & 1) ? hA : hB;
        const float* cin = (s & 1) ? cB : cA;
        float*      cout = (s & 1) ? cA : cB;
        lstm_step_kernel<<<dim3(16, 8, 2), 256, 0, stream>>>(lstm1out, 2 * UU, seq,
            l2f_Wi, l2f_Wh, l2f_b, l2b_Wi, l2b_Wh, l2b_b,
            hin, hout, cin, cout, nullptr, s);
    }
    // after 64 steps (s=63 odd → hout=hA), final h2 lives in hA

    concat_kernel<<<dim3(BB), 256, 0, stream>>>(pooled, hA, feats);
    dense_kernel<<<dim3(1024 / 32, BB / 32), 256, 0, stream>>>(feats, W1, b1, x1, BB, 1024, 3072, 1);
    dense_kernel<<<dim3(512 / 32, BB / 32), 256, 0, stream>>>(x1, W2, b2, x2, BB, 512, 1024, 1);
    final_kernel<<<dim3(BB), 256, 0, stream>>>(x2, W3, b3, (float*)d_out);
}

// Round 2
// 3610.743 us; speedup vs baseline: 3.1517x; 3.1517x over previous
//
#include <hip/hip_runtime.h>
#include <hip/hip_bf16.h>
#include <math.h>

#define BB 256
#define TT 64
#define UU 512

typedef __hip_bfloat16 bf16;
typedef __attribute__((ext_vector_type(8))) short short8;   // 8 x bf16 = 4 VGPRs
typedef __attribute__((ext_vector_type(4))) float floatx4;  // MFMA acc

__device__ __forceinline__ float sigmoidf_(float x) { return 1.0f / (1.0f + expf(-x)); }

// ---------------- transpose + fp32->bf16 convert ----------------
// in: [K x N] fp32 row-major. out: out[n * out_stride + k] = bf16(in[k][n]).
// grid (N/32, K/32), block 256.
__global__ void transpose_conv_kernel(const float* __restrict__ in, bf16* __restrict__ out,
                                      int K, int N, int out_stride) {
    __shared__ float tile[32][33];
    int k0 = blockIdx.y * 32;
    int n0 = blockIdx.x * 32;
    int tid = threadIdx.x;
    int nn = tid & 31, kk = tid >> 5;   // kk 0..7
    #pragma unroll
    for (int j = 0; j < 4; ++j)
        tile[kk + j * 8][nn] = in[(size_t)(k0 + kk + j * 8) * N + n0 + nn];
    __syncthreads();
    int kk2 = tid & 31, nn2 = tid >> 5;
    #pragma unroll
    for (int j = 0; j < 4; ++j)
        out[(size_t)(n0 + nn2 + j * 8) * out_stride + k0 + kk2] =
            __float2bfloat16(tile[kk2][nn2 + j * 8]);
}

// ---------------- mean-pool over 10x10 spatial ----------------
__global__ void pool_kernel(const float* __restrict__ enc, float* __restrict__ pooled) {
    int b = blockIdx.y;
    int e = blockIdx.x * 256 + threadIdx.x;
    const float* p = enc + (size_t)b * 100 * 2048 + e;
    float s = 0.f;
    #pragma unroll 4
    for (int i = 0; i < 100; ++i) s += p[(size_t)i * 2048];
    pooled[(size_t)b * 2048 + e] = s * 0.01f;
}

// ---------------- embedding gather -> bf16 ----------------
__global__ void embed_kernel(const int* __restrict__ seq, const float* __restrict__ emb,
                             bf16* __restrict__ tok) {
    int i = blockIdx.x;           // b*T + t
    int e = threadIdx.x;
    tok[(size_t)i * 256 + e] = __float2bfloat16(emb[(size_t)seq[i] * 256 + e]);
}

// ---------------- fused MFMA LSTM step ----------------
// z = [x_t, h] @ [Wi; Wh]^T(pre-transposed) + b; gates; mask carry.
// grid (UU/16=32, BB/64=4, 2 dirs), block 256 = 4 waves.
// Wave: 16 batch rows x 16 units x 4 gates -> 4 MFMAs per 32-wide K-chunk.
// Wt layout: [dir][n = g*512+u][Ktot] bf16, k-contiguous (B-fragment friendly).
__global__ __launch_bounds__(256)
void lstm_step_mfma(const bf16* __restrict__ x, int D, int Ktot,
                    const int* __restrict__ seq,
                    const bf16* __restrict__ Wt,
                    const float* __restrict__ bF, const float* __restrict__ bB,
                    const bf16* __restrict__ hin_all, bf16* __restrict__ hout_all,
                    const float* __restrict__ cin_all, float* __restrict__ cout_all,
                    bf16* __restrict__ seqout, int s) {
    const int dir = blockIdx.z;
    const int t = dir ? (TT - 1 - s) : s;
    const bf16* W = Wt + (size_t)dir * 2048 * Ktot;
    const float* bias = dir ? bB : bF;
    const bf16* hin = hin_all + (size_t)dir * BB * UU;
    bf16* hout = hout_all + (size_t)dir * BB * UU;
    const float* cin = cin_all + (size_t)dir * BB * UU;
    float* cout = cout_all + (size_t)dir * BB * UU;

    const int tid = threadIdx.x;
    const int wave = tid >> 6;
    const int lane = tid & 63;
    const int u0 = blockIdx.x * 16;
    const int rb = blockIdx.y * 64 + wave * 16;   // batch base for this wave

    const int lm = lane & 15;         // A row / C col
    const int lk = (lane >> 4) * 8;   // k offset within 32-chunk

    floatx4 acc[4] = {{0,0,0,0},{0,0,0,0},{0,0,0,0},{0,0,0,0}};

    const int arow = rb + lm;
    const bf16* xrow = x + ((size_t)arow * TT + t) * D;
    const bf16* hrow = hin + (size_t)arow * UU;
    const bf16* wrow0 = W + (size_t)(0 * UU + u0 + lm) * Ktot;
    const bf16* wrow1 = W + (size_t)(1 * UU + u0 + lm) * Ktot;
    const bf16* wrow2 = W + (size_t)(2 * UU + u0 + lm) * Ktot;
    const bf16* wrow3 = W + (size_t)(3 * UU + u0 + lm) * Ktot;

    for (int k0 = 0; k0 < Ktot; k0 += 32) {
        int k = k0 + lk;
        short8 a = (k < D) ? *(const short8*)(xrow + k)
                           : *(const short8*)(hrow + (k - D));
        short8 b0 = *(const short8*)(wrow0 + k);
        short8 b1 = *(const short8*)(wrow1 + k);
        short8 b2 = *(const short8*)(wrow2 + k);
        short8 b3 = *(const short8*)(wrow3 + k);
        acc[0] = __builtin_amdgcn_mfma_f32_16x16x32_bf16(a, b0, acc[0], 0, 0, 0);
        acc[1] = __builtin_amdgcn_mfma_f32_16x16x32_bf16(a, b1, acc[1], 0, 0, 0);
        acc[2] = __builtin_amdgcn_mfma_f32_16x16x32_bf16(a, b2, acc[2], 0, 0, 0);
        acc[3] = __builtin_amdgcn_mfma_f32_16x16x32_bf16(a, b3, acc[3], 0, 0, 0);
    }

    // epilogue: C/D layout col=lane&15, row=(lane>>4)*4+reg  [m89-verified]
    const int u = u0 + lm;
    const float bi = bias[0 * UU + u], bfg = bias[1 * UU + u];
    const float bg = bias[2 * UU + u], bo = bias[3 * UU + u];
    #pragma unroll
    for (int r = 0; r < 4; ++r) {
        int b = rb + (lane >> 4) * 4 + r;
        bool m = (seq[b * TT + t] != 0);
        float zi = acc[0][r] + bi;
        float zf = acc[1][r] + bfg;
        float zg = acc[2][r] + bg;
        float zo = acc[3][r] + bo;
        float cprev = cin[(size_t)b * UU + u];
        float hprev = __bfloat162float(hin[(size_t)b * UU + u]);
        float cnew = sigmoidf_(zf) * cprev + sigmoidf_(zi) * tanhf(zg);
        float hnew = sigmoidf_(zo) * tanhf(cnew);
        float hv = m ? hnew : hprev;
        float cv = m ? cnew : cprev;
        hout[(size_t)b * UU + u] = __float2bfloat16(hv);
        cout[(size_t)b * UU + u] = cv;
        if (seqout) seqout[((size_t)b * TT + t) * (2 * UU) + dir * UU + u] = __float2bfloat16(hv);
    }
}

// ---------------- dense MFMA: out = act(A @ Wt^T + b) ----------------
// A: [M x K] bf16 row-major. Wt: [N x K] bf16 (pre-transposed). out: [M x N] bf16.
// grid (N/64, M/64), block 256 = 4 waves; wave = 32x32 quadrant (2x2 MFMA frags).
__global__ __launch_bounds__(256)
void dense_mfma(const bf16* __restrict__ A, const bf16* __restrict__ Wt,
                const float* __restrict__ bias, bf16* __restrict__ out,
                int M, int N, int K, int relu) {
    const int tid = threadIdx.x;
    const int wave = tid >> 6, lane = tid & 63;
    const int r0 = blockIdx.y * 64 + (wave & 1) * 32;
    const int c0 = blockIdx.x * 64 + (wave >> 1) * 32;
    const int lm = lane & 15, lk = (lane >> 4) * 8;

    floatx4 acc[2][2] = {{{0,0,0,0},{0,0,0,0}},{{0,0,0,0},{0,0,0,0}}};
    const bf16* arow0 = A + (size_t)(r0 + lm) * K;
    const bf16* arow1 = A + (size_t)(r0 + 16 + lm) * K;
    const bf16* wrow0 = Wt + (size_t)(c0 + lm) * K;
    const bf16* wrow1 = Wt + (size_t)(c0 + 16 + lm) * K;

    for (int k0 = 0; k0 < K; k0 += 32) {
        short8 a0 = *(const short8*)(arow0 + k0 + lk);
        short8 a1 = *(const short8*)(arow1 + k0 + lk);
        short8 b0 = *(const short8*)(wrow0 + k0 + lk);
        short8 b1 = *(const short8*)(wrow1 + k0 + lk);
        acc[0][0] = __builtin_amdgcn_mfma_f32_16x16x32_bf16(a0, b0, acc[0][0], 0, 0, 0);
        acc[0][1] = __builtin_amdgcn_mfma_f32_16x16x32_bf16(a0, b1, acc[0][1], 0, 0, 0);
        acc[1][0] = __builtin_amdgcn_mfma_f32_16x16x32_bf16(a1, b0, acc[1][0], 0, 0, 0);
        acc[1][1] = __builtin_amdgcn_mfma_f32_16x16x32_bf16(a1, b1, acc[1][1], 0, 0, 0);
    }

    #pragma unroll
    for (int rf = 0; rf < 2; ++rf)
        #pragma unroll
        for (int cf = 0; cf < 2; ++cf)
            #pragma unroll
            for (int r = 0; r < 4; ++r) {
                int row = r0 + rf * 16 + (lane >> 4) * 4 + r;
                int col = c0 + cf * 16 + lm;
                float v = acc[rf][cf][r] + bias[col];
                if (relu) v = fmaxf(v, 0.f);
                out[(size_t)row * N + col] = __float2bfloat16(v);
            }
}

// ---------------- feats = [pooled | h2f | h2b] (bf16) ----------------
__global__ void concat_kernel(const float* __restrict__ pooled, const bf16* __restrict__ h2,
                              bf16* __restrict__ feats) {
    int b = blockIdx.x;
    for (int j = threadIdx.x; j < 3072; j += 256) {
        bf16 v;
        if (j < 2048) v = __float2bfloat16(pooled[(size_t)b * 2048 + j]);
        else {
            int u = j - 2048;
            int dir = u >> 9;
            int uu = u & 511;
            v = h2[((size_t)dir * BB + b) * UU + uu];
        }
        feats[(size_t)b * 3072 + j] = v;
    }
}

// ---------------- out = sigmoid(x2 @ W3 + b3), K=512 ----------------
__global__ void final_kernel(const bf16* __restrict__ x2, const float* __restrict__ W3,
                             const float* __restrict__ b3, float* __restrict__ out) {
    int b = blockIdx.x;
    int tid = threadIdx.x;
    float v = __bfloat162float(x2[(size_t)b * 512 + tid]) * W3[tid]
            + __bfloat162float(x2[(size_t)b * 512 + 256 + tid]) * W3[256 + tid];
    for (int off = 32; off > 0; off >>= 1) v += __shfl_down(v, off, 64);
    __shared__ float wsum[4];
    if ((tid & 63) == 0) wsum[tid >> 6] = v;
    __syncthreads();
    if (tid == 0) {
        float s = wsum[0] + wsum[1] + wsum[2] + wsum[3] + b3[0];
        out[b] = 1.0f / (1.0f + expf(-s));
    }
}

extern "C" void kernel_launch(void* const* d_in, const int* in_sizes, int n_in,
                              void* d_out, int out_size, void* d_ws, size_t ws_size,
                              hipStream_t stream) {
    const float* enc    = (const float*)d_in[0];
    const int*   seq    = (const int*)  d_in[1];
    const float* emb    = (const float*)d_in[2];
    const float* l1f_Wi = (const float*)d_in[3];
    const float* l1f_Wh = (const float*)d_in[4];
    const float* l1f_b  = (const float*)d_in[5];
    const float* l1b_Wi = (const float*)d_in[6];
    const float* l1b_Wh = (const float*)d_in[7];
    const float* l1b_b  = (const float*)d_in[8];
    const float* l2f_Wi = (const float*)d_in[9];
    const float* l2f_Wh = (const float*)d_in[10];
    const float* l2f_b  = (const float*)d_in[11];
    const float* l2b_Wi = (const float*)d_in[12];
    const float* l2b_Wh = (const float*)d_in[13];
    const float* l2b_b  = (const float*)d_in[14];
    const float* W1     = (const float*)d_in[15];
    const float* b1     = (const float*)d_in[16];
    const float* W2     = (const float*)d_in[17];
    const float* b2     = (const float*)d_in[18];
    const float* W3     = (const float*)d_in[19];
    const float* b3     = (const float*)d_in[20];

    // ---- workspace layout (bf16/fp32 mixed), ~77 MB ----
    char* p = (char*)d_ws;
    bf16* tok      = (bf16*)p;  p += (size_t)BB * TT * 256 * 2;        // 8.4 MB
    bf16* lstm1out = (bf16*)p;  p += (size_t)BB * TT * 1024 * 2;       // 33.6 MB
    bf16* Wt1      = (bf16*)p;  p += (size_t)2 * 2048 * 768 * 2;       // 6.3 MB
    bf16* Wt2      = (bf16*)p;  p += (size_t)2 * 2048 * 1536 * 2;      // 12.6 MB
    bf16* W1t      = (bf16*)p;  p += (size_t)1024 * 3072 * 2;          // 6.3 MB
    bf16* W2t      = (bf16*)p;  p += (size_t)512 * 1024 * 2;           // 1.0 MB
    float* pooled  = (float*)p; p += (size_t)BB * 2048 * 4;            // 2.1 MB
    bf16* feats    = (bf16*)p;  p += (size_t)BB * 3072 * 2;            // 1.6 MB
    bf16* x1       = (bf16*)p;  p += (size_t)BB * 1024 * 2;            // 0.5 MB
    bf16* x2       = (bf16*)p;  p += (size_t)BB * 512 * 2;             // 0.26 MB
    bf16* hA       = (bf16*)p;  p += (size_t)2 * BB * UU * 2;
    bf16* hB       = (bf16*)p;  p += (size_t)2 * BB * UU * 2;
    float* cA      = (float*)p; p += (size_t)2 * BB * UU * 4;
    float* cB      = (float*)p; p += (size_t)2 * BB * UU * 4;

    // ---- weight transpose/convert (one-time per call, ~13M elems total) ----
    // Wt layout per LSTM layer: [dir][n=g*512+u][Ktot], with k<D from Wi, k>=D from Wh.
    transpose_conv_kernel<<<dim3(64, 8),  256, 0, stream>>>(l1f_Wi, Wt1 + 0,                 256, 2048, 768);
    transpose_conv_kernel<<<dim3(64, 16), 256, 0, stream>>>(l1f_Wh, Wt1 + 256,               512, 2048, 768);
    transpose_conv_kernel<<<dim3(64, 8),  256, 0, stream>>>(l1b_Wi, Wt1 + (size_t)2048*768,       256, 2048, 768);
    transpose_conv_kernel<<<dim3(64, 16), 256, 0, stream>>>(l1b_Wh, Wt1 + (size_t)2048*768 + 256, 512, 2048, 768);
    transpose_conv_kernel<<<dim3(64, 32), 256, 0, stream>>>(l2f_Wi, Wt2 + 0,                 1024, 2048, 1536);
    transpose_conv_kernel<<<dim3(64, 16), 256, 0, stream>>>(l2f_Wh, Wt2 + 1024,              512, 2048, 1536);
    transpose_conv_kernel<<<dim3(64, 32), 256, 0, stream>>>(l2b_Wi, Wt2 + (size_t)2048*1536,        1024, 2048, 1536);
    transpose_conv_kernel<<<dim3(64, 16), 256, 0, stream>>>(l2b_Wh, Wt2 + (size_t)2048*1536 + 1024, 512, 2048, 1536);
    transpose_conv_kernel<<<dim3(32, 96), 256, 0, stream>>>(W1, W1t, 3072, 1024, 3072);
    transpose_conv_kernel<<<dim3(16, 32), 256, 0, stream>>>(W2, W2t, 1024, 512, 1024);

    pool_kernel<<<dim3(8, BB), 256, 0, stream>>>(enc, pooled);
    embed_kernel<<<dim3(BB * TT), 256, 0, stream>>>(seq, emb, tok);

    // -------- BiLSTM layer 1 (D=256, Ktot=768, writes lstm1out) --------
    hipMemsetAsync(hA, 0, (size_t)2 * BB * UU * 2, stream);
    hipMemsetAsync(cA, 0, (size_t)2 * BB * UU * 4, stream);
    for (int s = 0; s < TT; ++s) {
        const bf16* hin = (s & 1) ? hB : hA;
        bf16*      hout = (s & 1) ? hA : hB;
        const float* cin = (s & 1) ? cB : cA;
        float*      cout = (s & 1) ? cA : cB;
        lstm_step_mfma<<<dim3(32, 4, 2), 256, 0, stream>>>(tok, 256, 768, seq,
            Wt1, l1f_b, l1b_b, hin, hout, cin, cout, lstm1out, s);
    }

    // -------- BiLSTM layer 2 (D=1024, Ktot=1536, final state only) --------
    hipMemsetAsync(hA, 0, (size_t)2 * BB * UU * 2, stream);
    hipMemsetAsync(cA, 0, (size_t)2 * BB * UU * 4, stream);
    for (int s = 0; s < TT; ++s) {
        const bf16* hin = (s & 1) ? hB : hA;
        bf16*      hout = (s & 1) ? hA : hB;
        const float* cin = (s & 1) ? cB : cA;
        float*      cout = (s & 1) ? cA : cB;
        lstm_step_mfma<<<dim3(32, 4, 2), 256, 0, stream>>>(lstm1out, 1024, 1536, seq,
            Wt2, l2f_b, l2b_b, hin, hout, cin, cout, nullptr, s);
    }
    // after 64 steps (s=63 odd -> hout=hA), final h2 lives in hA

    concat_kernel<<<dim3(BB), 256, 0, stream>>>(pooled, hA, feats);
    dense_mfma<<<dim3(16, 4), 256, 0, stream>>>(feats, W1t, b1, x1, BB, 1024, 3072, 1);
    dense_mfma<<<dim3(8, 4),  256, 0, stream>>>(x1, W2t, b2, x2, BB, 512, 1024, 1);
    final_kernel<<<dim3(BB), 256, 0, stream>>>(x2, W3, b3, (float*)d_out);
}